// Round 15
// baseline (599.598 us; speedup 1.0000x reference)
//
#include <hip/hip_runtime.h>
#include <cstdint>
#include <cstddef>

#define HEADS 16
#define DH 64
#define BH 28
#define BWW 28
#define BATCH 32
#define HID 1024
#define M_ROWS 25088           // 32*28*28
#define ALPHA_C 0.082847664332725576f
#define EPS_C 1e-5f

typedef unsigned short ushort_t;
typedef __attribute__((ext_vector_type(8))) short bf16x8;     // 8 bf16 in 4 VGPRs
typedef __attribute__((ext_vector_type(4))) float f32x4;

__device__ inline unsigned short f2bf(float f) {
  unsigned int u = __builtin_bit_cast(unsigned int, f);
  u = (u + 0x7fffu + ((u >> 16) & 1u)) >> 16;   // RNE
  return (unsigned short)u;
}
__device__ inline float bf2f(unsigned short h) {
  unsigned int u = ((unsigned int)h) << 16;
  return __builtin_bit_cast(float, u);
}

// -------- dtype detect (bf16 vs fp32 bits) --------
__global__ __launch_bounds__(256) void detect_k(const ushort_t* __restrict__ x,
                                                const ushort_t* __restrict__ qw,
                                                int* __restrict__ flagp) {
  int tid = threadIdx.x;
  int big = 0;
  #pragma unroll
  for (int j = 0; j < 4; ++j) {
    float a = fabsf(bf2f(x[tid * 4 + j]));
    float b = fabsf(bf2f(qw[tid * 4 + j]));
    if (!(a < 1e3f)) big++;            // catches huge, Inf, NaN
    if (!(b < 1e3f)) big++;
  }
  __shared__ int cnt;
  if (tid == 0) cnt = 0;
  __syncthreads();
  if (big) atomicAdd(&cnt, big);
  __syncthreads();
  if (tid == 0) *flagp = (cnt == 0) ? 1 : 0;   // 1 = inputs are bf16
}

// -------- fused prep: convert x,img -> bf16 (fp32 mode only) + reduce over h --------
__global__ __launch_bounds__(256) void prep_k(const void* __restrict__ x,
                                              const void* __restrict__ img,
                                              const int* __restrict__ flagp,
                                              unsigned* __restrict__ x_bf,      // as bf16 pairs
                                              unsigned* __restrict__ img_bf,    // as bf16 pairs
                                              unsigned* __restrict__ xsum,      // bf16 pairs
                                              float2* __restrict__ imgsum) {
  const int blk = blockIdx.x;
  const int half = blk & 1;
  const int bw = blk >> 1;                   // b*28 + w
  const int b = bw / BWW, w = bw % BWW;
  const int c = half * 512 + threadIdx.x * 2;
  const size_t base2 = (((size_t)(b * BH * BWW) + w) * HID + c) >> 1;  // pair index
  const size_t hstr2 = (size_t)BWW * HID / 2;
  float sx0 = 0.f, sx1 = 0.f, si0 = 0.f, si1 = 0.f;
  if (*flagp) {
    const unsigned* xb = (const unsigned*)x;
    const unsigned* ib = (const unsigned*)img;
    for (int h = 0; h < BH; ++h) {
      unsigned ux = xb[base2 + h * hstr2];
      unsigned ui = ib[base2 + h * hstr2];
      sx0 += bf2f((ushort_t)(ux & 0xffffu)); sx1 += bf2f((ushort_t)(ux >> 16));
      si0 += bf2f((ushort_t)(ui & 0xffffu)); si1 += bf2f((ushort_t)(ui >> 16));
    }
  } else {
    const float2* xf = (const float2*)x;
    const float2* iff = (const float2*)img;
    for (int h = 0; h < BH; ++h) {
      float2 a = xf[base2 + h * hstr2];
      float2 g = iff[base2 + h * hstr2];
      x_bf[base2 + h * hstr2]   = ((unsigned)f2bf(a.y) << 16) | f2bf(a.x);
      img_bf[base2 + h * hstr2] = ((unsigned)f2bf(g.y) << 16) | f2bf(g.x);
      sx0 += a.x; sx1 += a.y;
      si0 += g.x; si1 += g.y;
    }
  }
  const size_t o2 = ((size_t)bw * HID + c) >> 1;
  xsum[o2] = ((unsigned)f2bf(sx1) << 16) | f2bf(sx0);
  imgsum[o2] = make_float2(si0 * ALPHA_C, si1 * ALPHA_C);
}

// -------- transpose either dtype -> bf16: dst[c*R+r] = src[r*C+c] --------
__global__ void transpose_any_k(const void* __restrict__ src, const int* __restrict__ flagp,
                                ushort_t* __restrict__ dst, int R, int C) {
  __shared__ float tile[32][33];
  int isbf = *flagp;
  int c0 = blockIdx.x * 32, r0 = blockIdx.y * 32;
  int tx = threadIdx.x, ty = threadIdx.y;
  const ushort_t* sb = (const ushort_t*)src;
  const float* sf = (const float*)src;
  #pragma unroll
  for (int i = ty; i < 32; i += 8) {
    size_t idx = (size_t)(r0 + i) * C + (c0 + tx);
    tile[i][tx] = isbf ? bf2f(sb[idx]) : sf[idx];
  }
  __syncthreads();
  #pragma unroll
  for (int i = ty; i < 32; i += 8)
    dst[(size_t)(c0 + i) * R + (r0 + tx)] = f2bf(tile[tx][i]);
}

#define BK 32

// stage one 128x32 A-tile and 128x32 B-tile into LDS (4 x 16B-wide async loads)
#define STAGE1(bufA, bufB, kk0) do {                                                             \
  const ushort_t* a0_ = aRow + (kk0);                                                            \
  const ushort_t* b0_ = bRow + (kk0);                                                            \
  __builtin_amdgcn_global_load_lds((const __attribute__((address_space(1))) unsigned int*)a0_,   \
      (__attribute__((address_space(3))) unsigned int*)((bufA) + tid * 8), 16, 0, 0);            \
  __builtin_amdgcn_global_load_lds((const __attribute__((address_space(1))) unsigned int*)(a0_ + (size_t)64 * K), \
      (__attribute__((address_space(3))) unsigned int*)((bufA) + 2048 + tid * 8), 16, 0, 0);     \
  __builtin_amdgcn_global_load_lds((const __attribute__((address_space(1))) unsigned int*)b0_,   \
      (__attribute__((address_space(3))) unsigned int*)((bufB) + tid * 8), 16, 0, 0);            \
  __builtin_amdgcn_global_load_lds((const __attribute__((address_space(1))) unsigned int*)(b0_ + (size_t)64 * K), \
      (__attribute__((address_space(3))) unsigned int*)((bufB) + 2048 + tid * 8), 16, 0, 0);     \
} while (0)

// -------- GEMM1: 8-phase 256x256 template (T2 swizzle + T3/T4 pipeline + T5) --------
// 8 waves (2M x 4N), BK=64, 128KB dbuf LDS. Per K-tile: 4 sub-phases of
// {ds_read quadrant | issue global_load_lds -> raw s_barrier -> lgkmcnt(0) ->
//  setprio(1) 16xMFMA setprio(0) -> barrier}; loads stay in flight across
// barriers; ONE vmcnt(0) per K-tile, 2 phases after last issue.
// T2: LDS rows are 128B -> 16-way conflict if linear; XOR-swizzle col-byte by
// (row&7)<<4 via PRE-SWIZZLED GLOBAL SOURCE (linear gload_lds dest) + swizzled
// ds_read addr (m201 pattern; both-sides-or-neither, rule #21).
#define GLQ(ld, gs) __builtin_amdgcn_global_load_lds( \
    (const __attribute__((address_space(1))) unsigned int*)(gs), \
    (__attribute__((address_space(3))) unsigned int*)(ld), 16, 0, 0)
#define RBAR() __builtin_amdgcn_s_barrier()
#define LK0()  do { asm volatile("s_waitcnt lgkmcnt(0)" ::: "memory"); \
                    __builtin_amdgcn_sched_barrier(0); } while (0)
#define VM0()  do { asm volatile("s_waitcnt vmcnt(0)" ::: "memory"); \
                    __builtin_amdgcn_sched_barrier(0); } while (0)

__global__ __launch_bounds__(512, 2) void gemm_qkv_k(const void* __restrict__ x_raw,
                                                     const ushort_t* __restrict__ x_bf,
                                                     const ushort_t* __restrict__ Bt,
                                                     const void* __restrict__ img_raw,
                                                     const ushort_t* __restrict__ img_bf,
                                                     const int* __restrict__ flagp,
                                                     ushort_t* __restrict__ qbuf,
                                                     ushort_t* __restrict__ kbuf) {
  __shared__ ushort_t As2[2][256 * 64];    // 64 KB
  __shared__ ushort_t Bs2[2][256 * 64];    // 64 KB
  const int tid = threadIdx.x;
  const int nt = blockIdx.x & 7;                        // 4 q-tiles + 4 k-tiles
  const int n0 = (nt < 4) ? nt * 256 : nt * 256 + 1024; // skip V band [1024,2048)
  const int m0 = (blockIdx.x >> 3) * 256;               // 98 m-tiles
  const int lane = tid & 63, wv = tid >> 6;
  const int fr = lane & 15, fq = lane >> 4;
  const int wr = wv >> 2, wc = wv & 3;                  // 2x4 wave grid
  const int isbf = *flagp;
  const ushort_t* A  = isbf ? (const ushort_t*)x_raw   : x_bf;
  const ushort_t* IM = isbf ? (const ushort_t*)img_raw : img_bf;

  // staging: thread t fills LDS elems [t*8, t*8+8) of a 64-row chunk (linear
  // dest); source column pre-swizzled so a swizzled READ sees logical data.
  const int srow = tid >> 3;                            // 0..63
  const int scol = ((tid & 7) * 8) ^ ((srow & 7) << 3); // element units
  const ushort_t* aG = A  + (size_t)(m0 + srow) * 1024 + scol;
  const ushort_t* bG = Bt + (size_t)(n0 + srow) * 1024 + scol;
  const int dOff = tid * 8;                             // LDS dest (elems)

  // swizzled frag-read offsets
  const int xr  = (fr & 7) << 3;
  const int cx0 = (fq * 8) ^ xr;                        // kh=0
  const int cx1 = (32 + fq * 8) ^ xr;                   // kh=1
  const int aBase = (wr * 128 + fr) * 64;
  const int bBase = (wc * 64 + fr) * 64;

  f32x4 acc[8][4] = {};

  // prologue: stage K-tile 0 into buf 0, full drain once
  {
    ushort_t* dA = As2[0]; ushort_t* dB = Bs2[0];
    #pragma unroll
    for (int j = 0; j < 4; ++j) GLQ(dA + j * 4096 + dOff, aG + (size_t)j * 65536);
    #pragma unroll
    for (int j = 0; j < 4; ++j) GLQ(dB + j * 4096 + dOff, bG + (size_t)j * 65536);
  }
  VM0();
  __syncthreads();

  #pragma unroll 2
  for (int kt = 0; kt < 16; ++kt) {
    const ushort_t* sA = As2[kt & 1];
    const ushort_t* sB = Bs2[kt & 1];
    ushort_t* dA = As2[(kt + 1) & 1];
    ushort_t* dB = Bs2[(kt + 1) & 1];
    const int ke = (kt + 1) * 64;
    const bool pf = kt < 15;
    bf16x8 af[4], bf0[4], bf1[4];

    // ---- P0: kh=0, mi 0-3 | stage A chunks 0,1,2 ----
    #pragma unroll
    for (int i = 0; i < 4; ++i) af[i]  = *(const bf16x8*)&sA[aBase + i * 1024 + cx0];
    #pragma unroll
    for (int i = 0; i < 4; ++i) bf0[i] = *(const bf16x8*)&sB[bBase + i * 1024 + cx0];
    if (pf) {
      GLQ(dA + dOff,            aG + ke);
      GLQ(dA +  4096 + dOff,    aG +  65536 + ke);
      GLQ(dA +  8192 + dOff,    aG + 131072 + ke);
    }
    RBAR(); LK0();
    __builtin_amdgcn_s_setprio(1);
    #pragma unroll
    for (int i = 0; i < 4; ++i)
      #pragma unroll
      for (int j = 0; j < 4; ++j)
        acc[i][j] = __builtin_amdgcn_mfma_f32_16x16x32_bf16(af[i], bf0[j], acc[i][j], 0, 0, 0);
    __builtin_amdgcn_s_setprio(0);
    RBAR();

    // ---- P1: kh=0, mi 4-7 | stage A chunk 3, B chunks 0,1 ----
    #pragma unroll
    for (int i = 0; i < 4; ++i) af[i] = *(const bf16x8*)&sA[aBase + (i + 4) * 1024 + cx0];
    if (pf) {
      GLQ(dA + 12288 + dOff,    aG + 196608 + ke);
      GLQ(dB + dOff,            bG + ke);
      GLQ(dB +  4096 + dOff,    bG +  65536 + ke);
    }
    RBAR(); LK0();
    __builtin_amdgcn_s_setprio(1);
    #pragma unroll
    for (int i = 0; i < 4; ++i)
      #pragma unroll
      for (int j = 0; j < 4; ++j)
        acc[i + 4][j] = __builtin_amdgcn_mfma_f32_16x16x32_bf16(af[i], bf0[j], acc[i + 4][j], 0, 0, 0);
    __builtin_amdgcn_s_setprio(0);
    RBAR();

    // ---- P2: kh=1, mi 0-3 | stage B chunks 2,3 ----
    #pragma unroll
    for (int i = 0; i < 4; ++i) af[i]  = *(const bf16x8*)&sA[aBase + i * 1024 + cx1];
    #pragma unroll
    for (int i = 0; i < 4; ++i) bf1[i] = *(const bf16x8*)&sB[bBase + i * 1024 + cx1];
    if (pf) {
      GLQ(dB +  8192 + dOff,    bG + 131072 + ke);
      GLQ(dB + 12288 + dOff,    bG + 196608 + ke);
    }
    RBAR(); LK0();
    __builtin_amdgcn_s_setprio(1);
    #pragma unroll
    for (int i = 0; i < 4; ++i)
      #pragma unroll
      for (int j = 0; j < 4; ++j)
        acc[i][j] = __builtin_amdgcn_mfma_f32_16x16x32_bf16(af[i], bf1[j], acc[i][j], 0, 0, 0);
    __builtin_amdgcn_s_setprio(0);
    RBAR();

    // ---- P3: kh=1, mi 4-7 | no stage; drain tile kt+1 before swap ----
    #pragma unroll
    for (int i = 0; i < 4; ++i) af[i] = *(const bf16x8*)&sA[aBase + (i + 4) * 1024 + cx1];
    RBAR(); LK0();
    __builtin_amdgcn_s_setprio(1);
    #pragma unroll
    for (int i = 0; i < 4; ++i)
      #pragma unroll
      for (int j = 0; j < 4; ++j)
        acc[i + 4][j] = __builtin_amdgcn_mfma_f32_16x16x32_bf16(af[i], bf1[j], acc[i + 4][j], 0, 0, 0);
    __builtin_amdgcn_s_setprio(0);
    if (pf) VM0();
    RBAR();
  }

  // ---- fused epilogue: +ALPHA*img (bf16), gamma on k, axial rope, store ----
  const int colg = n0 + wc * 64;         // 64-aligned: one head per wave
  const int t = colg >> 10;              // 0=q 2=k (wave-uniform; V removed)
  const int n = (colg & 1023) >> 6;      // head
  const float gamma = 1.0f - exp2f(-5.0f - (float)n);
  const float invf = powf(10000.0f, -(float)fr / 16.0f);

  #pragma unroll
  for (int mi = 0; mi < 8; ++mi) {
    #pragma unroll
    for (int r = 0; r < 4; ++r) {
      int m = m0 + wr * 128 + mi * 16 + fq * 4 + r;
      int b = m / 784, rem = m % 784;
      int h = rem / 28, w = rem % 28;
      size_t ibase = (size_t)m * HID + n * DH + fr;
      float v0 = acc[mi][0][r] + bf2f(IM[ibase])      * ALPHA_C;
      float v1 = acc[mi][1][r] + bf2f(IM[ibase + 16]) * ALPHA_C;
      float v2 = acc[mi][2][r] + bf2f(IM[ibase + 32]) * ALPHA_C;
      float v3 = acc[mi][3][r] + bf2f(IM[ibase + 48]) * ALPHA_C;
      if (t == 2) { v0 *= gamma; v1 *= gamma; v2 *= gamma; v3 *= gamma; }
      float snh, csh, snw, csw;
      __sincosf((float)h * invf, &snh, &csh);
      __sincosf((float)w * invf, &snw, &csw);
      float o0 = v0 * csh - v1 * snh;    // d=fr
      float o1 = v1 * csh + v0 * snh;    // d=fr+16
      float o2 = v2 * csw - v3 * snw;    // d=fr+32
      float o3 = v3 * csw + v2 * snw;    // d=fr+48
      ushort_t* dst = (t == 0 ? qbuf : kbuf) +
          (((((size_t)b * HEADS + n) * BH + h) * BWW + w) * DH) + fr;
      dst[0]  = f2bf(o0);
      dst[16] = f2bf(o1);
      dst[32] = f2bf(o2);
      dst[48] = f2bf(o3);
    }
  }
}

// -------- small GEMM for vsum: (32*28) x 1024 x 1024, C-init = ALPHA*imgsum --------
__global__ __launch_bounds__(256) void vsum_gemm_k(const ushort_t* __restrict__ A,   // xsum 896x1024 bf16
                                                   const ushort_t* __restrict__ Bt,  // w1T + 1024*1024 (V rows)
                                                   const float* __restrict__ imgsum, // 896x1024 fp32 (already *ALPHA)
                                                   float* __restrict__ vsum) {
  __shared__ ushort_t As[128 * BK];
  __shared__ ushort_t Bs[128 * BK];
  const int tid = threadIdx.x;
  const int K = 1024;
  const int n0 = (blockIdx.x % 8) * 128;
  const int m0 = (blockIdx.x / 8) * 128;
  const int lane = tid & 63;
  const int wave = tid >> 6;
  const int wm = (wave >> 1) * 64;
  const int wn = (wave & 1) * 64;
  const int fr = lane & 15;
  const int fq = lane >> 4;

  f32x4 acc[4][4] = {};
  const int srow = tid >> 2;
  const int skk  = (tid & 3) * 8;
  const ushort_t* aRow = A  + (size_t)(m0 + srow) * K + skk;
  const ushort_t* bRow = Bt + (size_t)(n0 + srow) * K + skk;

  for (int k0 = 0; k0 < K; k0 += BK) {
    __syncthreads();
    STAGE1(As, Bs, k0);
    __syncthreads();
    bf16x8 af[4], bfv[4];
    #pragma unroll
    for (int i = 0; i < 4; ++i)
      af[i] = *reinterpret_cast<const bf16x8*>(&As[(wm + i * 16 + fr) * BK + fq * 8]);
    #pragma unroll
    for (int i = 0; i < 4; ++i)
      bfv[i] = *reinterpret_cast<const bf16x8*>(&Bs[(wn + i * 16 + fr) * BK + fq * 8]);
    #pragma unroll
    for (int mi = 0; mi < 4; ++mi)
      #pragma unroll
      for (int ni = 0; ni < 4; ++ni)
        acc[mi][ni] = __builtin_amdgcn_mfma_f32_16x16x32_bf16(af[mi], bfv[ni], acc[mi][ni], 0, 0, 0);
  }

  #pragma unroll
  for (int mi = 0; mi < 4; ++mi)
    #pragma unroll
    for (int r = 0; r < 4; ++r) {
      int m = m0 + wm + mi * 16 + fq * 4 + r;     // b*28 + w
      int b = m / BWW, w = m % BWW;
      #pragma unroll
      for (int ni = 0; ni < 4; ++ni) {
        int col = n0 + wn + ni * 16 + fr;         // n*64 + d
        int n = col >> 6, d = col & 63;
        vsum[((((size_t)b * HEADS + n) * BWW) + w) * DH + d] =
            acc[mi][ni][r] + imgsum[(size_t)m * HID + col];
      }
    }
}

// -------- attention + fused GroupNorm: one block per (b,n), 8 waves --------
__global__ __launch_bounds__(512) void attn_k(const ushort_t* __restrict__ qbuf,
                                              const ushort_t* __restrict__ kbuf,
                                              const float* __restrict__ vsum,
                                              const void* __restrict__ gn_w,
                                              const void* __restrict__ gn_b,
                                              const int* __restrict__ flagp,
                                              ushort_t* __restrict__ xo) {
  __shared__ __align__(16) ushort_t outL[BH * BWW * DH];   // 100,352 B
  __shared__ ushort_t Vt[64 * 32];          // Vt[d][y] bf16, y in [0,32), pad zero
  __shared__ ushort_t Sa[8][32 * 32];       // per-wave S in MFMA A-layout (16 KB)
  __shared__ float rs[8][2];
  __shared__ float mu_s, rstd_s;
  const int bn = blockIdx.x;                // b*HEADS+n
  const int b = bn >> 4, n = bn & 15;
  const int tid = threadIdx.x;
  const int lane = tid & 63, wv = tid >> 6; // wv in 0..7
  const int fr = lane & 15, fq = lane >> 4;
  const size_t vbase = (size_t)bn * BWW * DH;

  for (int e = tid; e < 64 * 32; e += 512) {
    int d = e >> 5, y = e & 31;
    Vt[e] = (y < BWW) ? f2bf(vsum[vbase + (size_t)y * DH + d]) : (ushort_t)0;
  }
  __syncthreads();

  bf16x8 bv[4];
  #pragma unroll
  for (int i = 0; i < 4; ++i)
    bv[i] = *reinterpret_cast<const bf16x8*>(&Vt[(i * 16 + fr) * 32 + fq * 8]);

  float lsum = 0.f, lsq = 0.f;
  ushort_t* sa = Sa[wv];

  for (int hi = 0; hi < 4; ++hi) {
    const int h = wv + hi * 8;              // 0..31; each h<28 covered once
    const bool act = (h < BH);              // waves 4..7 idle at hi==3
    const size_t qb = ((size_t)bn * BH + (act ? h : 0)) * BWW * DH;

    if (act) {
      f32x4 s[2][2] = {};
      #pragma unroll
      for (int kk = 0; kk < 2; ++kk) {
        bf16x8 qf[2], kf[2];
        #pragma unroll
        for (int t = 0; t < 2; ++t) {
          qf[t] = *reinterpret_cast<const bf16x8*>(qbuf + qb + (size_t)(t * 16 + fr) * DH + kk * 32 + fq * 8);
          kf[t] = *reinterpret_cast<const bf16x8*>(kbuf + qb + (size_t)(t * 16 + fr) * DH + kk * 32 + fq * 8);
        }
        #pragma unroll
        for (int mt = 0; mt < 2; ++mt)
          #pragma unroll
          for (int nt = 0; nt < 2; ++nt)
            s[mt][nt] = __builtin_amdgcn_mfma_f32_16x16x32_bf16(qf[mt], kf[nt], s[mt][nt], 0, 0, 0);
      }

      #pragma unroll
      for (int mt = 0; mt < 2; ++mt)
        #pragma unroll
        for (int nt = 0; nt < 2; ++nt)
          #pragma unroll
          for (int r = 0; r < 4; ++r)
            sa[(mt * 16 + fq * 4 + r) * 32 + nt * 16 + fr] = f2bf(s[mt][nt][r]);
    }
    __syncthreads();   // uniform fence (all waves execute; Sa is wave-private)

    if (act) {
      f32x4 o[2][4] = {};
      #pragma unroll
      for (int mt = 0; mt < 2; ++mt) {
        bf16x8 af = *reinterpret_cast<const bf16x8*>(&sa[(mt * 16 + fr) * 32 + fq * 8]);
        #pragma unroll
        for (int nt = 0; nt < 4; ++nt)
          o[mt][nt] = __builtin_amdgcn_mfma_f32_16x16x32_bf16(af, bv[nt], o[mt][nt], 0, 0, 0);
      }

      #pragma unroll
      for (int mt = 0; mt < 2; ++mt)
        #pragma unroll
        for (int r = 0; r < 4; ++r) {
          int w_ = mt * 16 + fq * 4 + r;
          if (w_ < BWW) {
            ushort_t* dl = outL + ((size_t)(h * BWW + w_) * DH) + fr;
            #pragma unroll
            for (int nt = 0; nt < 4; ++nt) {
              float v = o[mt][nt][r];
              dl[nt * 16] = f2bf(v);
              lsum += v; lsq += v * v;
            }
          }
        }
    }
  }

  // block reduce -> mu/rstd
  #pragma unroll
  for (int off = 32; off > 0; off >>= 1) {
    lsum += __shfl_down(lsum, off);
    lsq  += __shfl_down(lsq, off);
  }
  if (lane == 0) { rs[wv][0] = lsum; rs[wv][1] = lsq; }
  __syncthreads();
  if (tid == 0) {
    float s = 0.f, q2 = 0.f;
    #pragma unroll
    for (int i = 0; i < 8; ++i) { s += rs[i][0]; q2 += rs[i][1]; }
    const float Ninv = 1.0f / (float)(BH * BWW * DH);
    float mu = s * Ninv;
    float var = q2 * Ninv - mu * mu;
    mu_s = mu;
    rstd_s = rsqrtf(var + EPS_C);
  }
  __syncthreads();

  // fused GN apply + relayout to (b,h,w,hid)
  const int isbf = *flagp;
  const float gw = isbf ? bf2f(((const ushort_t*)gn_w)[n]) : ((const float*)gn_w)[n];
  const float gb = isbf ? bf2f(((const ushort_t*)gn_b)[n]) : ((const float*)gn_b)[n];
  const float sc = rstd_s * gw;
  const float sh_ = gb - mu_s * sc;
  for (int c = tid; c < BH * BWW * 8; c += 512) {      // 6272 uint4-chunks
    int d8 = c & 7;
    int hw = c >> 3;
    int w = hw % BWW, h = hw / BWW;
    bf16x8 vv = *reinterpret_cast<const bf16x8*>(outL + (size_t)hw * DH + d8 * 8);
    union { ushort_t u[8]; uint4 q4; } o;
    #pragma unroll
    for (int j = 0; j < 8; ++j)
      o.u[j] = f2bf(bf2f((ushort_t)vv[j]) * sc + sh_);
    *(uint4*)(xo + (((size_t)(b * BH + h) * BWW + w) * HID) + n * DH + d8 * 8) = o.q4;
  }
}

// -------- plain GEMM (used for GEMM2), dyn output dtype, single-buffer --------
__global__ __launch_bounds__(256) void gemm_bt_k(const ushort_t* __restrict__ A,
                                                 const ushort_t* __restrict__ Bt,
                                                 void* __restrict__ Cv,
                                                 const int* __restrict__ flagp,
                                                 int M, int N, int K) {
  __shared__ ushort_t As[128 * BK];
  __shared__ ushort_t Bs[128 * BK];
  const int tid = threadIdx.x;
  const int ntile = N / 128;
  const int n0 = (blockIdx.x % ntile) * 128;
  const int m0 = (blockIdx.x / ntile) * 128;
  const int lane = tid & 63;
  const int wave = tid >> 6;
  const int wm = (wave >> 1) * 64;
  const int wn = (wave & 1) * 64;
  const int fr = lane & 15;
  const int fq = lane >> 4;

  f32x4 acc[4][4] = {};
  const int srow = tid >> 2;
  const int skk  = (tid & 3) * 8;
  const ushort_t* aRow = A  + (size_t)(m0 + srow) * K + skk;
  const ushort_t* bRow = Bt + (size_t)(n0 + srow) * K + skk;

  for (int k0 = 0; k0 < K; k0 += BK) {
    __syncthreads();
    STAGE1(As, Bs, k0);
    __syncthreads();
    bf16x8 af[4], bfv[4];
    #pragma unroll
    for (int i = 0; i < 4; ++i)
      af[i] = *reinterpret_cast<const bf16x8*>(&As[(wm + i * 16 + fr) * BK + fq * 8]);
    #pragma unroll
    for (int i = 0; i < 4; ++i)
      bfv[i] = *reinterpret_cast<const bf16x8*>(&Bs[(wn + i * 16 + fr) * BK + fq * 8]);
    #pragma unroll
    for (int mi = 0; mi < 4; ++mi)
      #pragma unroll
      for (int ni = 0; ni < 4; ++ni)
        acc[mi][ni] = __builtin_amdgcn_mfma_f32_16x16x32_bf16(af[mi], bfv[ni], acc[mi][ni], 0, 0, 0);
  }

  int isbf = *flagp;
  if (isbf) {
    ushort_t* C = (ushort_t*)Cv;
    #pragma unroll
    for (int mi = 0; mi < 4; ++mi)
      #pragma unroll
      for (int r = 0; r < 4; ++r) {
        int m = m0 + wm + mi * 16 + fq * 4 + r;
        ushort_t* crow = C + (size_t)m * N + n0 + wn + fr;
        #pragma unroll
        for (int ni = 0; ni < 4; ++ni) crow[ni * 16] = f2bf(acc[mi][ni][r]);
      }
  } else {
    float* C = (float*)Cv;
    #pragma unroll
    for (int mi = 0; mi < 4; ++mi)
      #pragma unroll
      for (int r = 0; r < 4; ++r) {
        int m = m0 + wm + mi * 16 + fq * 4 + r;
        float* crow = C + (size_t)m * N + n0 + wn + fr;
        #pragma unroll
        for (int ni = 0; ni < 4; ++ni) crow[ni * 16] = acc[mi][ni][r];
      }
  }
}

// -------- launch --------
extern "C" void kernel_launch(void* const* d_in, const int* in_sizes, int n_in,
                              void* d_out, int out_size, void* d_ws, size_t ws_size,
                              hipStream_t stream) {
  const void* x     = d_in[0];
  const void* img   = d_in[1];
  const void* qkv_w = d_in[2];
  const void* o_w   = d_in[3];
  const void* gn_w  = d_in[4];
  const void* gn_b  = d_in[5];

  char* ws = (char*)d_ws;
  // layout (bytes), peak 217,579,776 (<= 217,583,872 round-3-proven budget):
  ushort_t* x_bf   = (ushort_t*)(ws);                 // 51,380,224; dead after gemm1
  ushort_t* xo     = (ushort_t*)(ws);                 // overlays dead x_bf (written by attn_k)
  ushort_t* qbuf   = (ushort_t*)(ws + 51380224);      // 51,380,224 (written by gemm_qkv_k)
  //   xsum/imgsum overlay qbuf: both dead before gemm_qkv_k runs (vsum_gemm precedes it)
  ushort_t* xsum   = (ushort_t*)(ws + 51380224);      //  1,835,008
  float*    imgsum = (float*)(ws + 53215232);         //  3,670,016
  ushort_t* kbuf   = (ushort_t*)(ws + 102760448);     // 51,380,224
  float*    vsum   = (float*)(ws + 154140672);        //  3,670,016 (917,504 floats)
  int*      flag   = (int*)(ws + 157810688);          //        256
  ushort_t* w1T    = (ushort_t*)(ws + 157810944);     //  6,291,456
  ushort_t* w2T    = (ushort_t*)(ws + 164102400);     //  2,097,152
  ushort_t* img_bf = (ushort_t*)(ws + 166199552);     // 51,380,224 (end 217,579,776)

  detect_k<<<1, 256, 0, stream>>>((const ushort_t*)x, (const ushort_t*)qkv_w, flag);
  prep_k<<<BATCH * BWW * 2, 256, 0, stream>>>(x, img, flag,
      (unsigned*)x_bf, (unsigned*)img_bf, (unsigned*)xsum, (float2*)imgsum);
  transpose_any_k<<<dim3(96, 32), dim3(32, 8), 0, stream>>>(qkv_w, flag, w1T, 1024, 3072);
  transpose_any_k<<<dim3(32, 32), dim3(32, 8), 0, stream>>>(o_w, flag, w2T, 1024, 1024);

  vsum_gemm_k<<<56, 256, 0, stream>>>(xsum, w1T + (size_t)1024 * 1024, imgsum, vsum);
  gemm_qkv_k<<<98 * 8, 512, 0, stream>>>(x, x_bf, w1T, img, img_bf, flag, qbuf, kbuf);

  attn_k<<<BATCH * HEADS, 512, 0, stream>>>(qbuf, kbuf, vsum, gn_w, gn_b, flag, xo);
  gemm_bt_k<<<196 * 8, 256, 0, stream>>>(xo, w2T, d_out, flag, M_ROWS, 1024, 1024);
}

// Round 16
// 586.375 us; speedup vs baseline: 1.0226x; 1.0226x over previous
//
#include <hip/hip_runtime.h>
#include <cstdint>
#include <cstddef>

#define HEADS 16
#define DH 64
#define BH 28
#define BWW 28
#define BATCH 32
#define HID 1024
#define M_ROWS 25088           // 32*28*28
#define ALPHA_C 0.082847664332725576f
#define EPS_C 1e-5f

typedef unsigned short ushort_t;
typedef __attribute__((ext_vector_type(8))) short bf16x8;     // 8 bf16 in 4 VGPRs
typedef __attribute__((ext_vector_type(4))) float f32x4;

__device__ inline unsigned short f2bf(float f) {
  unsigned int u = __builtin_bit_cast(unsigned int, f);
  u = (u + 0x7fffu + ((u >> 16) & 1u)) >> 16;   // RNE
  return (unsigned short)u;
}
__device__ inline float bf2f(unsigned short h) {
  unsigned int u = ((unsigned int)h) << 16;
  return __builtin_bit_cast(float, u);
}

// -------- dtype detect (bf16 vs fp32 bits) --------
__global__ __launch_bounds__(256) void detect_k(const ushort_t* __restrict__ x,
                                                const ushort_t* __restrict__ qw,
                                                int* __restrict__ flagp) {
  int tid = threadIdx.x;
  int big = 0;
  #pragma unroll
  for (int j = 0; j < 4; ++j) {
    float a = fabsf(bf2f(x[tid * 4 + j]));
    float b = fabsf(bf2f(qw[tid * 4 + j]));
    if (!(a < 1e3f)) big++;            // catches huge, Inf, NaN
    if (!(b < 1e3f)) big++;
  }
  __shared__ int cnt;
  if (tid == 0) cnt = 0;
  __syncthreads();
  if (big) atomicAdd(&cnt, big);
  __syncthreads();
  if (tid == 0) *flagp = (cnt == 0) ? 1 : 0;   // 1 = inputs are bf16
}

// -------- fused prep: convert x,img -> bf16 (fp32 mode only) + reduce over h --------
__global__ __launch_bounds__(256) void prep_k(const void* __restrict__ x,
                                              const void* __restrict__ img,
                                              const int* __restrict__ flagp,
                                              unsigned* __restrict__ x_bf,      // as bf16 pairs
                                              unsigned* __restrict__ img_bf,    // as bf16 pairs
                                              unsigned* __restrict__ xsum,      // bf16 pairs
                                              float2* __restrict__ imgsum) {
  const int blk = blockIdx.x;
  const int half = blk & 1;
  const int bw = blk >> 1;                   // b*28 + w
  const int b = bw / BWW, w = bw % BWW;
  const int c = half * 512 + threadIdx.x * 2;
  const size_t base2 = (((size_t)(b * BH * BWW) + w) * HID + c) >> 1;  // pair index
  const size_t hstr2 = (size_t)BWW * HID / 2;
  float sx0 = 0.f, sx1 = 0.f, si0 = 0.f, si1 = 0.f;
  if (*flagp) {
    const unsigned* xb = (const unsigned*)x;
    const unsigned* ib = (const unsigned*)img;
    for (int h = 0; h < BH; ++h) {
      unsigned ux = xb[base2 + h * hstr2];
      unsigned ui = ib[base2 + h * hstr2];
      sx0 += bf2f((ushort_t)(ux & 0xffffu)); sx1 += bf2f((ushort_t)(ux >> 16));
      si0 += bf2f((ushort_t)(ui & 0xffffu)); si1 += bf2f((ushort_t)(ui >> 16));
    }
  } else {
    const float2* xf = (const float2*)x;
    const float2* iff = (const float2*)img;
    for (int h = 0; h < BH; ++h) {
      float2 a = xf[base2 + h * hstr2];
      float2 g = iff[base2 + h * hstr2];
      x_bf[base2 + h * hstr2]   = ((unsigned)f2bf(a.y) << 16) | f2bf(a.x);
      img_bf[base2 + h * hstr2] = ((unsigned)f2bf(g.y) << 16) | f2bf(g.x);
      sx0 += a.x; sx1 += a.y;
      si0 += g.x; si1 += g.y;
    }
  }
  const size_t o2 = ((size_t)bw * HID + c) >> 1;
  xsum[o2] = ((unsigned)f2bf(sx1) << 16) | f2bf(sx0);
  imgsum[o2] = make_float2(si0 * ALPHA_C, si1 * ALPHA_C);
}

// -------- transpose either dtype -> bf16: dst[c*R+r] = src[r*C+c] --------
__global__ void transpose_any_k(const void* __restrict__ src, const int* __restrict__ flagp,
                                ushort_t* __restrict__ dst, int R, int C) {
  __shared__ float tile[32][33];
  int isbf = *flagp;
  int c0 = blockIdx.x * 32, r0 = blockIdx.y * 32;
  int tx = threadIdx.x, ty = threadIdx.y;
  const ushort_t* sb = (const ushort_t*)src;
  const float* sf = (const float*)src;
  #pragma unroll
  for (int i = ty; i < 32; i += 8) {
    size_t idx = (size_t)(r0 + i) * C + (c0 + tx);
    tile[i][tx] = isbf ? bf2f(sb[idx]) : sf[idx];
  }
  __syncthreads();
  #pragma unroll
  for (int i = ty; i < 32; i += 8)
    dst[(size_t)(c0 + i) * R + (r0 + tx)] = f2bf(tile[tx][i]);
}

#define BK 32

// stage one 128x32 A-tile and 128x32 B-tile into LDS (4 x 16B-wide async loads)
#define STAGE1(bufA, bufB, kk0) do {                                                             \
  const ushort_t* a0_ = aRow + (kk0);                                                            \
  const ushort_t* b0_ = bRow + (kk0);                                                            \
  __builtin_amdgcn_global_load_lds((const __attribute__((address_space(1))) unsigned int*)a0_,   \
      (__attribute__((address_space(3))) unsigned int*)((bufA) + tid * 8), 16, 0, 0);            \
  __builtin_amdgcn_global_load_lds((const __attribute__((address_space(1))) unsigned int*)(a0_ + (size_t)64 * K), \
      (__attribute__((address_space(3))) unsigned int*)((bufA) + 2048 + tid * 8), 16, 0, 0);     \
  __builtin_amdgcn_global_load_lds((const __attribute__((address_space(1))) unsigned int*)b0_,   \
      (__attribute__((address_space(3))) unsigned int*)((bufB) + tid * 8), 16, 0, 0);            \
  __builtin_amdgcn_global_load_lds((const __attribute__((address_space(1))) unsigned int*)(b0_ + (size_t)64 * K), \
      (__attribute__((address_space(3))) unsigned int*)((bufB) + 2048 + tid * 8), 16, 0, 0);     \
} while (0)

// -------- GEMM1 (q,k bands only: N=2048) + fused rope/gamma epilogue --------
// single-buffer 2-barrier 128^2 loop — PROVEN 173-175us. R15 verdict: 8-phase
// 256^2 port ran 186us (conflicts 1.3e7->0 but occupancy 39->17.6, MfmaUtil
// 26.5->23.8): at 1 block/CU with K=1024 the barrier-heavy pipeline loses to
// this structure's implicit 3-blocks/CU wave overlap. GEMM1 structure CLOSED.
__global__ __launch_bounds__(256) void gemm_qkv_k(const void* __restrict__ x_raw,
                                                  const ushort_t* __restrict__ x_bf,
                                                  const ushort_t* __restrict__ Bt,
                                                  const void* __restrict__ img_raw,
                                                  const ushort_t* __restrict__ img_bf,
                                                  const int* __restrict__ flagp,
                                                  ushort_t* __restrict__ qbuf,
                                                  ushort_t* __restrict__ kbuf) {
  __shared__ ushort_t As[128 * BK];
  __shared__ ushort_t Bs[128 * BK];
  const int tid = threadIdx.x;
  const int K = 1024;
  const int ntile = 16;                              // 8 q-tiles + 8 k-tiles
  const int nt = blockIdx.x % ntile;
  const int n0 = (nt < 8) ? nt * 128 : nt * 128 + 1024;   // skip V band [1024,2048)
  const int m0 = (blockIdx.x / ntile) * 128;
  const int lane = tid & 63;
  const int wave = tid >> 6;
  const int wm = (wave >> 1) * 64;
  const int wn = (wave & 1) * 64;
  const int fr = lane & 15;
  const int fq = lane >> 4;
  const int isbf = *flagp;
  const ushort_t* A  = isbf ? (const ushort_t*)x_raw   : x_bf;
  const ushort_t* IM = isbf ? (const ushort_t*)img_raw : img_bf;

  f32x4 acc[4][4] = {};
  const int srow = tid >> 2;
  const int skk  = (tid & 3) * 8;
  const ushort_t* aRow = A  + (size_t)(m0 + srow) * K + skk;
  const ushort_t* bRow = Bt + (size_t)(n0 + srow) * K + skk;

  for (int k0 = 0; k0 < K; k0 += BK) {
    __syncthreads();
    STAGE1(As, Bs, k0);
    __syncthreads();
    bf16x8 af[4], bfv[4];
    #pragma unroll
    for (int i = 0; i < 4; ++i)
      af[i] = *reinterpret_cast<const bf16x8*>(&As[(wm + i * 16 + fr) * BK + fq * 8]);
    #pragma unroll
    for (int i = 0; i < 4; ++i)
      bfv[i] = *reinterpret_cast<const bf16x8*>(&Bs[(wn + i * 16 + fr) * BK + fq * 8]);
    #pragma unroll
    for (int mi = 0; mi < 4; ++mi)
      #pragma unroll
      for (int ni = 0; ni < 4; ++ni)
        acc[mi][ni] = __builtin_amdgcn_mfma_f32_16x16x32_bf16(af[mi], bfv[ni], acc[mi][ni], 0, 0, 0);
  }

  // ---- fused epilogue: +ALPHA*img (bf16), gamma on k, axial rope, store bf16 ----
  const int colg = n0 + wn;              // 64-aligned
  const int t = colg >> 10;              // 0=q 2=k (wave-uniform; V removed)
  const int n = (colg & 1023) >> 6;      // head
  const float gamma = 1.0f - exp2f(-5.0f - (float)n);
  const float invf = powf(10000.0f, -(float)fr / 16.0f);

  #pragma unroll
  for (int mi = 0; mi < 4; ++mi) {
    #pragma unroll
    for (int r = 0; r < 4; ++r) {
      int m = m0 + wm + mi * 16 + fq * 4 + r;
      int b = m / 784, rem = m % 784;
      int h = rem / 28, w = rem % 28;
      size_t ibase = (size_t)m * HID + n * DH + fr;
      float v0 = acc[mi][0][r] + bf2f(IM[ibase])      * ALPHA_C;
      float v1 = acc[mi][1][r] + bf2f(IM[ibase + 16]) * ALPHA_C;
      float v2 = acc[mi][2][r] + bf2f(IM[ibase + 32]) * ALPHA_C;
      float v3 = acc[mi][3][r] + bf2f(IM[ibase + 48]) * ALPHA_C;
      if (t == 2) { v0 *= gamma; v1 *= gamma; v2 *= gamma; v3 *= gamma; }
      float snh, csh, snw, csw;
      __sincosf((float)h * invf, &snh, &csh);
      __sincosf((float)w * invf, &snw, &csw);
      float o0 = v0 * csh - v1 * snh;    // d=fr
      float o1 = v1 * csh + v0 * snh;    // d=fr+16
      float o2 = v2 * csw - v3 * snw;    // d=fr+32
      float o3 = v3 * csw + v2 * snw;    // d=fr+48
      ushort_t* dst = (t == 0 ? qbuf : kbuf) +
          (((((size_t)b * HEADS + n) * BH + h) * BWW + w) * DH) + fr;
      dst[0]  = f2bf(o0);
      dst[16] = f2bf(o1);
      dst[32] = f2bf(o2);
      dst[48] = f2bf(o3);
    }
  }
}

// -------- small GEMM for vsum: (32*28) x 1024 x 1024, C-init = ALPHA*imgsum --------
__global__ __launch_bounds__(256) void vsum_gemm_k(const ushort_t* __restrict__ A,   // xsum 896x1024 bf16
                                                   const ushort_t* __restrict__ Bt,  // w1T + 1024*1024 (V rows)
                                                   const float* __restrict__ imgsum, // 896x1024 fp32 (already *ALPHA)
                                                   float* __restrict__ vsum) {
  __shared__ ushort_t As[128 * BK];
  __shared__ ushort_t Bs[128 * BK];
  const int tid = threadIdx.x;
  const int K = 1024;
  const int n0 = (blockIdx.x % 8) * 128;
  const int m0 = (blockIdx.x / 8) * 128;
  const int lane = tid & 63;
  const int wave = tid >> 6;
  const int wm = (wave >> 1) * 64;
  const int wn = (wave & 1) * 64;
  const int fr = lane & 15;
  const int fq = lane >> 4;

  f32x4 acc[4][4] = {};
  const int srow = tid >> 2;
  const int skk  = (tid & 3) * 8;
  const ushort_t* aRow = A  + (size_t)(m0 + srow) * K + skk;
  const ushort_t* bRow = Bt + (size_t)(n0 + srow) * K + skk;

  for (int k0 = 0; k0 < K; k0 += BK) {
    __syncthreads();
    STAGE1(As, Bs, k0);
    __syncthreads();
    bf16x8 af[4], bfv[4];
    #pragma unroll
    for (int i = 0; i < 4; ++i)
      af[i] = *reinterpret_cast<const bf16x8*>(&As[(wm + i * 16 + fr) * BK + fq * 8]);
    #pragma unroll
    for (int i = 0; i < 4; ++i)
      bfv[i] = *reinterpret_cast<const bf16x8*>(&Bs[(wn + i * 16 + fr) * BK + fq * 8]);
    #pragma unroll
    for (int mi = 0; mi < 4; ++mi)
      #pragma unroll
      for (int ni = 0; ni < 4; ++ni)
        acc[mi][ni] = __builtin_amdgcn_mfma_f32_16x16x32_bf16(af[mi], bfv[ni], acc[mi][ni], 0, 0, 0);
  }

  #pragma unroll
  for (int mi = 0; mi < 4; ++mi)
    #pragma unroll
    for (int r = 0; r < 4; ++r) {
      int m = m0 + wm + mi * 16 + fq * 4 + r;     // b*28 + w
      int b = m / BWW, w = m % BWW;
      #pragma unroll
      for (int ni = 0; ni < 4; ++ni) {
        int col = n0 + wn + ni * 16 + fr;         // n*64 + d
        int n = col >> 6, d = col & 63;
        vsum[((((size_t)b * HEADS + n) * BWW) + w) * DH + d] =
            acc[mi][ni][r] + imgsum[(size_t)m * HID + col];
      }
    }
}

// -------- attention + fused GroupNorm: one block per (b,n), 8 waves --------
// R15: removed the per-iteration __syncthreads. Sa[wv] is WAVE-PRIVATE, so the
// S round-trip needs only same-wave lgkmcnt ordering (compiler emits it) — the
// barrier only forced 8 waves into lockstep each h-iter, killing cross-wave
// MFMA/VALU/mem overlap (m114). End-of-kernel barriers still order outL.
__global__ __launch_bounds__(512) void attn_k(const ushort_t* __restrict__ qbuf,
                                              const ushort_t* __restrict__ kbuf,
                                              const float* __restrict__ vsum,
                                              const void* __restrict__ gn_w,
                                              const void* __restrict__ gn_b,
                                              const int* __restrict__ flagp,
                                              ushort_t* __restrict__ xo) {
  __shared__ __align__(16) ushort_t outL[BH * BWW * DH];   // 100,352 B
  __shared__ ushort_t Vt[64 * 32];          // Vt[d][y] bf16, y in [0,32), pad zero
  __shared__ ushort_t Sa[8][32 * 32];       // per-wave S in MFMA A-layout (16 KB)
  __shared__ float rs[8][2];
  __shared__ float mu_s, rstd_s;
  const int bn = blockIdx.x;                // b*HEADS+n
  const int b = bn >> 4, n = bn & 15;
  const int tid = threadIdx.x;
  const int lane = tid & 63, wv = tid >> 6; // wv in 0..7
  const int fr = lane & 15, fq = lane >> 4;
  const size_t vbase = (size_t)bn * BWW * DH;

  for (int e = tid; e < 64 * 32; e += 512) {
    int d = e >> 5, y = e & 31;
    Vt[e] = (y < BWW) ? f2bf(vsum[vbase + (size_t)y * DH + d]) : (ushort_t)0;
  }
  __syncthreads();

  bf16x8 bv[4];
  #pragma unroll
  for (int i = 0; i < 4; ++i)
    bv[i] = *reinterpret_cast<const bf16x8*>(&Vt[(i * 16 + fr) * 32 + fq * 8]);

  float lsum = 0.f, lsq = 0.f;
  ushort_t* sa = Sa[wv];

  for (int hi = 0; hi < 4; ++hi) {
    const int h = wv + hi * 8;              // 0..31; each h<28 covered once
    if (h < BH) {
      const size_t qb = ((size_t)bn * BH + h) * BWW * DH;

      // S = Q K^T  (pad rows/cols produce garbage that lands on zero V pad)
      f32x4 s[2][2] = {};
      #pragma unroll
      for (int kk = 0; kk < 2; ++kk) {
        bf16x8 qf[2], kf[2];
        #pragma unroll
        for (int t = 0; t < 2; ++t) {
          qf[t] = *reinterpret_cast<const bf16x8*>(qbuf + qb + (size_t)(t * 16 + fr) * DH + kk * 32 + fq * 8);
          kf[t] = *reinterpret_cast<const bf16x8*>(kbuf + qb + (size_t)(t * 16 + fr) * DH + kk * 32 + fq * 8);
        }
        #pragma unroll
        for (int mt = 0; mt < 2; ++mt)
          #pragma unroll
          for (int nt = 0; nt < 2; ++nt)
            s[mt][nt] = __builtin_amdgcn_mfma_f32_16x16x32_bf16(qf[mt], kf[nt], s[mt][nt], 0, 0, 0);
      }

      // C-layout -> A-layout via wave-PRIVATE LDS tile (no barrier needed:
      // same-wave ds_write->ds_read ordered via lgkmcnt by the compiler)
      #pragma unroll
      for (int mt = 0; mt < 2; ++mt)
        #pragma unroll
        for (int nt = 0; nt < 2; ++nt)
          #pragma unroll
          for (int r = 0; r < 4; ++r)
            sa[(mt * 16 + fq * 4 + r) * 32 + nt * 16 + fr] = f2bf(s[mt][nt][r]);

      f32x4 o[2][4] = {};
      #pragma unroll
      for (int mt = 0; mt < 2; ++mt) {
        bf16x8 af = *reinterpret_cast<const bf16x8*>(&sa[(mt * 16 + fr) * 32 + fq * 8]);
        #pragma unroll
        for (int nt = 0; nt < 4; ++nt)
          o[mt][nt] = __builtin_amdgcn_mfma_f32_16x16x32_bf16(af, bv[nt], o[mt][nt], 0, 0, 0);
      }

      #pragma unroll
      for (int mt = 0; mt < 2; ++mt)
        #pragma unroll
        for (int r = 0; r < 4; ++r) {
          int w_ = mt * 16 + fq * 4 + r;
          if (w_ < BWW) {
            ushort_t* dl = outL + ((size_t)(h * BWW + w_) * DH) + fr;
            #pragma unroll
            for (int nt = 0; nt < 4; ++nt) {
              float v = o[mt][nt][r];
              dl[nt * 16] = f2bf(v);
              lsum += v; lsq += v * v;
            }
          }
        }
    }
  }

  // block reduce -> mu/rstd
  #pragma unroll
  for (int off = 32; off > 0; off >>= 1) {
    lsum += __shfl_down(lsum, off);
    lsq  += __shfl_down(lsq, off);
  }
  if (lane == 0) { rs[wv][0] = lsum; rs[wv][1] = lsq; }
  __syncthreads();
  if (tid == 0) {
    float s = 0.f, q2 = 0.f;
    #pragma unroll
    for (int i = 0; i < 8; ++i) { s += rs[i][0]; q2 += rs[i][1]; }
    const float Ninv = 1.0f / (float)(BH * BWW * DH);
    float mu = s * Ninv;
    float var = q2 * Ninv - mu * mu;
    mu_s = mu;
    rstd_s = rsqrtf(var + EPS_C);
  }
  __syncthreads();

  // fused GN apply + relayout to (b,h,w,hid)
  const int isbf = *flagp;
  const float gw = isbf ? bf2f(((const ushort_t*)gn_w)[n]) : ((const float*)gn_w)[n];
  const float gb = isbf ? bf2f(((const ushort_t*)gn_b)[n]) : ((const float*)gn_b)[n];
  const float sc = rstd_s * gw;
  const float sh_ = gb - mu_s * sc;
  for (int c = tid; c < BH * BWW * 8; c += 512) {      // 6272 uint4-chunks
    int d8 = c & 7;
    int hw = c >> 3;
    int w = hw % BWW, h = hw / BWW;
    bf16x8 vv = *reinterpret_cast<const bf16x8*>(outL + (size_t)hw * DH + d8 * 8);
    union { ushort_t u[8]; uint4 q4; } o;
    #pragma unroll
    for (int j = 0; j < 8; ++j)
      o.u[j] = f2bf(bf2f((ushort_t)vv[j]) * sc + sh_);
    *(uint4*)(xo + (((size_t)(b * BH + h) * BWW + w) * HID) + n * DH + d8 * 8) = o.q4;
  }
}

// -------- plain GEMM (used for GEMM2), dyn output dtype, single-buffer --------
__global__ __launch_bounds__(256) void gemm_bt_k(const ushort_t* __restrict__ A,
                                                 const ushort_t* __restrict__ Bt,
                                                 void* __restrict__ Cv,
                                                 const int* __restrict__ flagp,
                                                 int M, int N, int K) {
  __shared__ ushort_t As[128 * BK];
  __shared__ ushort_t Bs[128 * BK];
  const int tid = threadIdx.x;
  const int ntile = N / 128;
  const int n0 = (blockIdx.x % ntile) * 128;
  const int m0 = (blockIdx.x / ntile) * 128;
  const int lane = tid & 63;
  const int wave = tid >> 6;
  const int wm = (wave >> 1) * 64;
  const int wn = (wave & 1) * 64;
  const int fr = lane & 15;
  const int fq = lane >> 4;

  f32x4 acc[4][4] = {};
  const int srow = tid >> 2;
  const int skk  = (tid & 3) * 8;
  const ushort_t* aRow = A  + (size_t)(m0 + srow) * K + skk;
  const ushort_t* bRow = Bt + (size_t)(n0 + srow) * K + skk;

  for (int k0 = 0; k0 < K; k0 += BK) {
    __syncthreads();
    STAGE1(As, Bs, k0);
    __syncthreads();
    bf16x8 af[4], bfv[4];
    #pragma unroll
    for (int i = 0; i < 4; ++i)
      af[i] = *reinterpret_cast<const bf16x8*>(&As[(wm + i * 16 + fr) * BK + fq * 8]);
    #pragma unroll
    for (int i = 0; i < 4; ++i)
      bfv[i] = *reinterpret_cast<const bf16x8*>(&Bs[(wn + i * 16 + fr) * BK + fq * 8]);
    #pragma unroll
    for (int mi = 0; mi < 4; ++mi)
      #pragma unroll
      for (int ni = 0; ni < 4; ++ni)
        acc[mi][ni] = __builtin_amdgcn_mfma_f32_16x16x32_bf16(af[mi], bfv[ni], acc[mi][ni], 0, 0, 0);
  }

  int isbf = *flagp;
  if (isbf) {
    ushort_t* C = (ushort_t*)Cv;
    #pragma unroll
    for (int mi = 0; mi < 4; ++mi)
      #pragma unroll
      for (int r = 0; r < 4; ++r) {
        int m = m0 + wm + mi * 16 + fq * 4 + r;
        ushort_t* crow = C + (size_t)m * N + n0 + wn + fr;
        #pragma unroll
        for (int ni = 0; ni < 4; ++ni) crow[ni * 16] = f2bf(acc[mi][ni][r]);
      }
  } else {
    float* C = (float*)Cv;
    #pragma unroll
    for (int mi = 0; mi < 4; ++mi)
      #pragma unroll
      for (int r = 0; r < 4; ++r) {
        int m = m0 + wm + mi * 16 + fq * 4 + r;
        float* crow = C + (size_t)m * N + n0 + wn + fr;
        #pragma unroll
        for (int ni = 0; ni < 4; ++ni) crow[ni * 16] = acc[mi][ni][r];
      }
  }
}

// -------- launch --------
extern "C" void kernel_launch(void* const* d_in, const int* in_sizes, int n_in,
                              void* d_out, int out_size, void* d_ws, size_t ws_size,
                              hipStream_t stream) {
  const void* x     = d_in[0];
  const void* img   = d_in[1];
  const void* qkv_w = d_in[2];
  const void* o_w   = d_in[3];
  const void* gn_w  = d_in[4];
  const void* gn_b  = d_in[5];

  char* ws = (char*)d_ws;
  // layout (bytes), peak 217,579,776 (<= 217,583,872 round-3-proven budget):
  ushort_t* x_bf   = (ushort_t*)(ws);                 // 51,380,224; dead after gemm1
  ushort_t* xo     = (ushort_t*)(ws);                 // overlays dead x_bf (written by attn_k)
  ushort_t* qbuf   = (ushort_t*)(ws + 51380224);      // 51,380,224 (written by gemm_qkv_k)
  //   xsum/imgsum overlay qbuf: both dead before gemm_qkv_k runs (vsum_gemm precedes it)
  ushort_t* xsum   = (ushort_t*)(ws + 51380224);      //  1,835,008
  float*    imgsum = (float*)(ws + 53215232);         //  3,670,016
  ushort_t* kbuf   = (ushort_t*)(ws + 102760448);     // 51,380,224
  float*    vsum   = (float*)(ws + 154140672);        //  3,670,016 (917,504 floats)
  int*      flag   = (int*)(ws + 157810688);          //        256
  ushort_t* w1T    = (ushort_t*)(ws + 157810944);     //  6,291,456
  ushort_t* w2T    = (ushort_t*)(ws + 164102400);     //  2,097,152
  ushort_t* img_bf = (ushort_t*)(ws + 166199552);     // 51,380,224 (end 217,579,776)

  detect_k<<<1, 256, 0, stream>>>((const ushort_t*)x, (const ushort_t*)qkv_w, flag);
  prep_k<<<BATCH * BWW * 2, 256, 0, stream>>>(x, img, flag,
      (unsigned*)x_bf, (unsigned*)img_bf, (unsigned*)xsum, (float2*)imgsum);
  transpose_any_k<<<dim3(96, 32), dim3(32, 8), 0, stream>>>(qkv_w, flag, w1T, 1024, 3072);
  transpose_any_k<<<dim3(32, 32), dim3(32, 8), 0, stream>>>(o_w, flag, w2T, 1024, 1024);

  vsum_gemm_k<<<56, 256, 0, stream>>>(xsum, w1T + (size_t)1024 * 1024, imgsum, vsum);
  gemm_qkv_k<<<196 * 16, 256, 0, stream>>>(x, x_bf, w1T, img, img_bf, flag, qbuf, kbuf);

  attn_k<<<BATCH * HEADS, 512, 0, stream>>>(qbuf, kbuf, vsum, gn_w, gn_b, flag, xo);
  gemm_bt_k<<<196 * 8, 256, 0, stream>>>(xo, w2T, d_out, flag, M_ROWS, 1024, 1024);
}